// Round 2
// baseline (125.198 us; speedup 1.0000x reference)
//
#include <hip/hip_runtime.h>
#include <hip/hip_cooperative_groups.h>

// Problem constants: B=4, Nc=1024, Nf=8192, fp32 in/out.
#define B  4
#define NF 8192
#define NC 1024
#define TJ (NF / 32)          // 256 y row-tiles per batch
#define TPW (TJ / 8)          // 32 y-tiles per wave (8 waves/block)
#define XT 256                // x columns per block (8 col-frags of 32)

#define NCRS (B * NC)

typedef _Float16 h8   __attribute__((ext_vector_type(8)));
typedef float    f16v __attribute__((ext_vector_type(16)));

namespace cg = cooperative_groups;

// ---------------------------------------------------------------------------
// Single cooperative kernel (256 blocks x 512 thr = 1 block/CU, co-resident).
// Phase 0: build y A-frags (131072 items = exactly one per thread), coarse-
//          loss wave partials into LDS, zero out[]; grid.sync() (device-scope
//          fence -> cross-XCD frag visibility).
// Phase 1: swapped-operand MFMA chamfer, XT=256 (halves fragbuf re-reads vs
//          XT=128), fused fine-sum epilogue, 1 atomic per block.
// d(i,j) inside one mfma_f32_32x32x16_f16 via augmented K-slots (validated):
//   A (y, plain):  k[ yh0 yh1 yh2 yl0 yl1 yl2 yh0 yh1 | yh2 syh syl 1 1 0 0 0]
//   B (x, m=-2x):  k[ mh0 mh1 mh2 mh0 mh1 mh2 ml0 ml1 | ml2 1 1 sxh sxl 0 0 0]
// acc[row=y][col=x] ~= d (err ~2^-21); min over y = register fold (v_min3)
// + one shfl_xor(32). Region (bx&7) -> XCD affinity for y-frag L2 locality.
// ---------------------------------------------------------------------------

__global__ __launch_bounds__(512) void k_fused(const float* __restrict__ rf,
                                               const float* __restrict__ gf,
                                               const float* __restrict__ rc,
                                               const float* __restrict__ gc,
                                               h8* __restrict__ fragbuf,
                                               float* __restrict__ out) {
    __shared__ float rbuf[8][XT];
    __shared__ float crs[8];
    __shared__ float fsum[4];

    int bx = blockIdx.x;         // 256 = 8 regions * 32 xgroups
    int t  = threadIdx.x;
    int ln = t & 63, w = t >> 6, m = ln & 31, kg = ln >> 5;

    // ---------------- phase 0: fragbuf build + coarse partials ------------
    {
        int id  = bx * 512 + t;          // 0..131071, frag lane == ln
        int src = id >> 16;              // 0 = gf, 1 = rf
        int pb  = (id >> 14) & 3;
        int jt  = (id >> 6) & (TJ - 1);

        const float* y = (src ? rf : gf) + ((size_t)(pb * NF) + jt * 32 + m) * 3;
        float y0 = y[0], y1 = y[1], y2 = y[2];
        _Float16 h0 = (_Float16)y0, h1 = (_Float16)y1, h2 = (_Float16)y2;
        _Float16 l0 = (_Float16)(y0 - (float)h0);
        _Float16 l1 = (_Float16)(y1 - (float)h1);
        _Float16 l2 = (_Float16)(y2 - (float)h2);
        float sy = fmaf(y0, y0, fmaf(y1, y1, y2 * y2));
        _Float16 sh = (_Float16)sy;
        _Float16 sl = (_Float16)(sy - (float)sh);

        h8 fr = {};
        if (kg == 0) {
            fr[0] = h0; fr[1] = h1; fr[2] = h2;
            fr[3] = l0; fr[4] = l1; fr[5] = l2;
            fr[6] = h0; fr[7] = h1;
        } else {
            fr[0] = h2; fr[1] = sh; fr[2] = sl;
            fr[3] = (_Float16)1.0f; fr[4] = (_Float16)1.0f;
        }
        fragbuf[((size_t)(src * B + pb) * TJ + jt) * 64 + ln] = fr;

        // Coarse L2 point loss partials: ids 0..4095 = blocks 0..7 exactly.
        if (bx < 8) {
            float dx = rc[3 * id + 0] - gc[3 * id + 0];
            float dy = rc[3 * id + 1] - gc[3 * id + 1];
            float dz = rc[3 * id + 2] - gc[3 * id + 2];
            float s = sqrtf(fmaf(dx, dx, fmaf(dy, dy, dz * dz)));
#pragma unroll
            for (int off = 32; off > 0; off >>= 1) s += __shfl_down(s, off);
            if (ln == 0) crs[w] = s;     // persists across grid.sync()
        }
        if (bx == 0 && t == 0) { out[0] = 0.0f; out[1] = 0.0f; }
    }
    cg::this_grid().sync();   // device-scope: frag writes visible cross-XCD

    // ---------------- phase 1: chamfer main ------------------------------
    int reg = bx & 7;            // region -> XCD affinity (dispatch ~ bx%8)
    int dir = reg >> 2;
    int b   = reg & 3;
    int xg  = bx >> 3;           // 0..31

    // B fragments (m = -2x encoding) for the block's 256 x-cols.
    const float* xp = dir ? gf : rf;
    h8 bfr[8];
#pragma unroll
    for (int f = 0; f < 8; ++f) {
        const float* xr = xp + ((size_t)(b * NF) + xg * XT + f * 32 + m) * 3;
        float x0 = xr[0], x1 = xr[1], x2 = xr[2];
        float t0 = -2.0f * x0, t1 = -2.0f * x1, t2 = -2.0f * x2;
        _Float16 mh0 = (_Float16)t0, mh1 = (_Float16)t1, mh2 = (_Float16)t2;
        _Float16 ml0 = (_Float16)(t0 - (float)mh0);
        _Float16 ml1 = (_Float16)(t1 - (float)mh1);
        _Float16 ml2 = (_Float16)(t2 - (float)mh2);
        float sx = fmaf(x0, x0, fmaf(x1, x1, x2 * x2));
        _Float16 sh = (_Float16)sx;
        _Float16 sl = (_Float16)(sx - (float)sh);
        h8 fr = {};
        if (kg == 0) {
            fr[0] = mh0; fr[1] = mh1; fr[2] = mh2;
            fr[3] = mh0; fr[4] = mh1; fr[5] = mh2;
            fr[6] = ml0; fr[7] = ml1;
        } else {
            fr[0] = ml2; fr[1] = (_Float16)1.0f; fr[2] = (_Float16)1.0f;
            fr[3] = sh;  fr[4] = sl;
        }
        bfr[f] = fr;
    }

    float mn[8];
#pragma unroll
    for (int f = 0; f < 8; ++f) mn[f] = 3.4e38f;

    // Main loop: wave w owns y-tile pairs; per pair: 2 loads (prefetched)
    // + 16 MFMA + in-register min3 folds (min-axis = rows = regs).
    const h8* p = fragbuf + ((size_t)(dir * B + b) * TJ + w * TPW) * 64 + ln;
    h8 a0 = p[0];
    h8 a1 = p[64];
#pragma unroll 2
    for (int q = 0; q < TPW / 2; ++q) {
        // Unconditional prefetch of the next pair (fragbuf tail-padded 2KB).
        h8 n0 = p[(2 * q + 2) * 64];
        h8 n1 = p[(2 * q + 3) * 64];
#pragma unroll
        for (int f = 0; f < 8; ++f) {
            f16v c0 = __builtin_amdgcn_mfma_f32_32x32x16_f16(a0, bfr[f], (f16v){}, 0, 0, 0);
            f16v c1 = __builtin_amdgcn_mfma_f32_32x32x16_f16(a1, bfr[f], (f16v){}, 0, 0, 0);
            float pa = fminf(c0[0], c1[0]);
            float pb = fminf(c0[1], c1[1]);
#pragma unroll
            for (int r = 2; r < 16; r += 2) {
                pa = fminf(fminf(c0[r], c1[r]), pa);       // v_min3_f32
                pb = fminf(fminf(c0[r + 1], c1[r + 1]), pb);
            }
            mn[f] = fminf(fminf(pa, pb), mn[f]);
        }
        a0 = n0;
        a1 = n1;
    }

    // Epilogue: lane^32 holds complementary rows -> one shuffle; min across
    // waves via LDS; sqrt; block-level SUM; ONE atomic per block.
#pragma unroll
    for (int f = 0; f < 8; ++f) {
        float v = fminf(mn[f], __shfl_xor(mn[f], 32));
        if (kg == 0) rbuf[w][f * 32 + m] = v;
    }
    __syncthreads();
    if (t < XT) {        // waves 0..3, all 64 lanes active
        float v = rbuf[0][t];
#pragma unroll
        for (int ww = 1; ww < 8; ++ww) v = fminf(v, rbuf[ww][t]);
        float s = sqrtf(fmaxf(v, 0.0f));
#pragma unroll
        for (int off = 32; off > 0; off >>= 1) s += __shfl_down(s, off);
        if (ln == 0) fsum[w] = s;
    }
    __syncthreads();
    if (t == 0) {
        float fine = fsum[0] + fsum[1] + fsum[2] + fsum[3];
        atomicAdd(&out[1], fine * (0.5f / (float)(B * NF)));   // loss_fine
        if (bx < 8) {
            float c = crs[0] + crs[1] + crs[2] + crs[3]
                    + crs[4] + crs[5] + crs[6] + crs[7];
            atomicAdd(&out[0], c * (1.0f / (float)NCRS));      // loss_coarse
        }
    }
}

extern "C" void kernel_launch(void* const* d_in, const int* in_sizes, int n_in,
                              void* d_out, int out_size, void* d_ws, size_t ws_size,
                              hipStream_t stream) {
    const float* rc = (const float*)d_in[0];  // ret_coarse [4,1024,3]
    const float* rf = (const float*)d_in[1];  // ret_fine   [4,8192,3]
    const float* gf = (const float*)d_in[2];  // gt_fine    [4,8192,3]
    const float* gc = (const float*)d_in[3];  // gt_coarse  [4,1024,3]

    h8*    fragbuf = (h8*)d_ws;               // 2 MB (+2KB pad for prefetch)
    float* out     = (float*)d_out;

    void* args[] = {(void*)&rf, (void*)&gf, (void*)&rc, (void*)&gc,
                    (void*)&fragbuf, (void*)&out};
    hipLaunchCooperativeKernel((const void*)k_fused, dim3(256), dim3(512),
                               args, 0, stream);
}

// Round 3
// 81.431 us; speedup vs baseline: 1.5375x; 1.5375x over previous
//
#include <hip/hip_runtime.h>

// Problem constants: B=4, Nc=1024, Nf=8192, fp32 in/out.
#define B  4
#define NF 8192
#define NC 1024
#define TJ (NF / 32)          // 256 y row-tiles per batch
#define TPW (TJ / 8)          // 32 y-tiles per wave (8 waves/block)
#define XT 128                // x columns per block (4 col-frags of 32)

#define NCRS (B * NC)

typedef _Float16 h8   __attribute__((ext_vector_type(8)));
typedef float    f16v __attribute__((ext_vector_type(16)));

// ---------------------------------------------------------------------------
// Two-kernel swapped-operand MFMA chamfer (validated round 1: 87.1 us,
// absmax 0.0). Round 3: memset dispatch eliminated (3 -> 2 dispatches):
//   - coarse partials -> plain stores to ws (no zero/atomic), summed by
//     k_main block 0's epilogue thread.
//   - out[1] zeroed by a single k_prep thread (stream order -> visible).
// Round-2 lesson: XT=256 single-block/CU fusion collapses to 2 waves/SIMD +
// VGPR pressure (68 regs, serialized MFMA) -> 50 us. Keep XT=128, 512 blocks.
//
// d(i,j) inside one mfma_f32_32x32x16_f16 via augmented K-slots:
//   A (y, plain):  k[ yh0 yh1 yh2 yl0 yl1 yl2 yh0 yh1 | yh2 syh syl 1 1 0 0 0]
//   B (x, m=-2x):  k[ mh0 mh1 mh2 mh0 mh1 mh2 ml0 ml1 | ml2 1 1 sxh sxl 0 0 0]
// acc[row=y][col=x] ~= d (err ~2^-21); min over y = register v_min3 fold +
// one shfl_xor(32). Region (bx&7) -> XCD affinity for y-frag L2 locality.
// ---------------------------------------------------------------------------

// Build A-layout (plain) y-fragments for both point sets: src 0 = gf, 1 = rf.
__global__ __launch_bounds__(256) void k_prep(const float* __restrict__ rf,
                                              const float* __restrict__ gf,
                                              h8* __restrict__ fragbuf,
                                              const float* __restrict__ rc,
                                              const float* __restrict__ gc,
                                              float* __restrict__ crs_ws,
                                              float* __restrict__ out) {
    int id  = blockIdx.x * 256 + threadIdx.x;   // 131072 total
    int src = id >> 16;
    int rem = id & 65535;
    int b   = rem >> 14;
    int jt  = (rem >> 6) & (TJ - 1);
    int ln  = rem & 63;
    int n   = ln & 31, kg = ln >> 5;

    const float* y = (src ? rf : gf) + ((size_t)(b * NF) + jt * 32 + n) * 3;
    float y0 = y[0], y1 = y[1], y2 = y[2];
    _Float16 h0 = (_Float16)y0, h1 = (_Float16)y1, h2 = (_Float16)y2;
    _Float16 l0 = (_Float16)(y0 - (float)h0);
    _Float16 l1 = (_Float16)(y1 - (float)h1);
    _Float16 l2 = (_Float16)(y2 - (float)h2);
    float sy = fmaf(y0, y0, fmaf(y1, y1, y2 * y2));
    _Float16 sh = (_Float16)sy;
    _Float16 sl = (_Float16)(sy - (float)sh);

    h8 fr = {};
    if (kg == 0) {
        fr[0] = h0; fr[1] = h1; fr[2] = h2;
        fr[3] = l0; fr[4] = l1; fr[5] = l2;
        fr[6] = h0; fr[7] = h1;
    } else {
        fr[0] = h2; fr[1] = sh; fr[2] = sl;
        fr[3] = (_Float16)1.0f; fr[4] = (_Float16)1.0f;
    }
    fragbuf[((size_t)(src * B + b) * TJ + jt) * 64 + ln] = fr;

    // Coarse L2 point partials: ids 0..4095 = blocks 0..15 exactly (block-
    // uniform branch). Per-wave partial -> PLAIN store (no zero, no atomic).
    if (id < NCRS) {
        float dx = rc[3 * id + 0] - gc[3 * id + 0];
        float dy = rc[3 * id + 1] - gc[3 * id + 1];
        float dz = rc[3 * id + 2] - gc[3 * id + 2];
        float s = sqrtf(fmaf(dx, dx, fmaf(dy, dy, dz * dz)));
#pragma unroll
        for (int off = 32; off > 0; off >>= 1) s += __shfl_down(s, off);
        if ((threadIdx.x & 63) == 0)
            crs_ws[id >> 6] = s;                 // 64 wave partials
    }
    if (id == 0) out[1] = 0.0f;                  // zero for k_main's atomics
}

__global__ __launch_bounds__(512) void k_main(const float* __restrict__ rf,
                                              const float* __restrict__ gf,
                                              const h8* __restrict__ fragbuf,
                                              const float* __restrict__ crs_ws,
                                              float* __restrict__ out) {
    __shared__ float rbuf[8][XT];
    __shared__ float fsum[2];

    int bx  = blockIdx.x;        // 512 = 64 xgroups * 8 regions
    int reg = bx & 7;            // region -> XCD affinity (dispatch ~ bx%8)
    int dir = reg >> 2;
    int b   = reg & 3;
    int xg  = bx >> 3;           // 0..63
    int t   = threadIdx.x;
    int ln = t & 63, w = t >> 6, m = ln & 31, kg = ln >> 5;

    // ---- B fragments (m = -2x encoding) for the block's 128 x-cols -------
    const float* xp = dir ? gf : rf;
    h8 bfr[4];
#pragma unroll
    for (int f = 0; f < 4; ++f) {
        const float* xr = xp + ((size_t)(b * NF) + xg * XT + f * 32 + m) * 3;
        float x0 = xr[0], x1 = xr[1], x2 = xr[2];
        float t0 = -2.0f * x0, t1 = -2.0f * x1, t2 = -2.0f * x2;
        _Float16 mh0 = (_Float16)t0, mh1 = (_Float16)t1, mh2 = (_Float16)t2;
        _Float16 ml0 = (_Float16)(t0 - (float)mh0);
        _Float16 ml1 = (_Float16)(t1 - (float)mh1);
        _Float16 ml2 = (_Float16)(t2 - (float)mh2);
        float sx = fmaf(x0, x0, fmaf(x1, x1, x2 * x2));
        _Float16 sh = (_Float16)sx;
        _Float16 sl = (_Float16)(sx - (float)sh);
        h8 fr = {};
        if (kg == 0) {
            fr[0] = mh0; fr[1] = mh1; fr[2] = mh2;
            fr[3] = mh0; fr[4] = mh1; fr[5] = mh2;
            fr[6] = ml0; fr[7] = ml1;
        } else {
            fr[0] = ml2; fr[1] = (_Float16)1.0f; fr[2] = (_Float16)1.0f;
            fr[3] = sh;  fr[4] = sl;
        }
        bfr[f] = fr;
    }

    float mn[4];
#pragma unroll
    for (int f = 0; f < 4; ++f) mn[f] = 3.4e38f;

    // ---- main loop: wave w owns y-tile pairs; per pair: 2 loads (prefetched)
    //      + 8 MFMA + in-register min3 folds (min-axis = rows = regs).
    const h8* p = fragbuf + ((size_t)(dir * B + b) * TJ + w * TPW) * 64 + ln;
    h8 a0 = p[0];
    h8 a1 = p[64];
#pragma unroll 2
    for (int q = 0; q < TPW / 2; ++q) {
        // Unconditional prefetch of the next pair (fragbuf tail-padded 2KB).
        h8 n0 = p[(2 * q + 2) * 64];
        h8 n1 = p[(2 * q + 3) * 64];
#pragma unroll
        for (int f = 0; f < 4; ++f) {
            f16v c0 = __builtin_amdgcn_mfma_f32_32x32x16_f16(a0, bfr[f], (f16v){}, 0, 0, 0);
            f16v c1 = __builtin_amdgcn_mfma_f32_32x32x16_f16(a1, bfr[f], (f16v){}, 0, 0, 0);
            float pa = fminf(c0[0], c1[0]);
            float pb = fminf(c0[1], c1[1]);
#pragma unroll
            for (int r = 2; r < 16; r += 2) {
                pa = fminf(fminf(c0[r], c1[r]), pa);       // v_min3_f32
                pb = fminf(fminf(c0[r + 1], c1[r + 1]), pb);
            }
            mn[f] = fminf(fminf(pa, pb), mn[f]);
        }
        a0 = n0;
        a1 = n1;
    }

    // ---- epilogue: lane^32 holds complementary rows -> one shuffle; min
    // across waves via LDS; sqrt; block SUM; one atomic per block. ----------
#pragma unroll
    for (int f = 0; f < 4; ++f) {
        float v = fminf(mn[f], __shfl_xor(mn[f], 32));
        if (kg == 0) rbuf[w][f * 32 + m] = v;
    }
    __syncthreads();
    if (t < XT) {        // waves 0..1, all 64 lanes active
        float v = rbuf[0][t];
#pragma unroll
        for (int ww = 1; ww < 8; ++ww) v = fminf(v, rbuf[ww][t]);
        float s = sqrtf(fmaxf(v, 0.0f));
#pragma unroll
        for (int off = 32; off > 0; off >>= 1) s += __shfl_down(s, off);
        if (ln == 0) fsum[w] = s;
    }
    __syncthreads();
    if (t == 0) {
        atomicAdd(&out[1], (fsum[0] + fsum[1]) * (0.5f / (float)(B * NF)));
        if (bx == 0) {               // coarse final: sum 64 ws partials
            float c = 0.f;
#pragma unroll
            for (int i = 0; i < 64; ++i) c += crs_ws[i];
            out[0] = c * (1.0f / (float)NCRS);
        }
    }
}

extern "C" void kernel_launch(void* const* d_in, const int* in_sizes, int n_in,
                              void* d_out, int out_size, void* d_ws, size_t ws_size,
                              hipStream_t stream) {
    const float* rc = (const float*)d_in[0];  // ret_coarse [4,1024,3]
    const float* rf = (const float*)d_in[1];  // ret_fine   [4,8192,3]
    const float* gf = (const float*)d_in[2];  // gt_fine    [4,8192,3]
    const float* gc = (const float*)d_in[3];  // gt_coarse  [4,1024,3]

    h8*    fragbuf = (h8*)d_ws;               // 2 MB (+2KB pad for prefetch)
    float* crs_ws  = (float*)((char*)d_ws + (2u << 20) + 4096);  // 64 floats
    float* out     = (float*)d_out;

    k_prep<<<512, 256, 0, stream>>>(rf, gf, fragbuf, rc, gc, crs_ws, out);
    k_main<<<512, 512, 0, stream>>>(rf, gf, fragbuf, crs_ws, out);
}